// Round 9
// baseline (4037.696 us; speedup 1.0000x reference)
//
#include <hip/hip_runtime.h>

// Single-launch fused LSTM for MI355X.  B=32, T=1024, D_IN=512, H=512.
//
// R13 = R12 with the LDS-cast compile error fixed (flat u32* + index
// helper; R12 cast smem to a 4-D array pointer but indexed 5 dims).
//
//   Grid 256 WGs x 256 thr:
//     WG 0..63   : R11 recurrence, all 1024 steps (no chunk restarts).
//                  h exchange: self-validating 8B records, split-poll
//                  (32/wave) + LDS pair-exchange + 1 barrier (R11, proven).
//     WG 64..255 : pregate producers.  192 = 32 col-blocks x 6 t-slices
//                  (WG handles cb for t = tslice + 6k).  4 waves =
//                  (batch-half, gate-pair); bfrag 2x16 per wave.
//   preg ring: 512 t-slots (134 MB).  Cross-XCD visibility: preg written
//   and read with AGENT-scope u64 atomics (normal stores would strand in
//   the writer XCD's non-coherent L2).
//   preg->recur ready: pflag[t*32+cb] = t+1 (EXACT-MATCH, poison-immune).
//   Producer orders tile-stores-before-flag via __syncthreads (vmcnt(0)
//   drain before s_barrier) + RELEASE flag store.  Consumer polls 32 flags
//   with one coalesced 128B load; pregate runs ~3x faster per t than recur
//   consumes -> first-try pass in steady state.
//   Ring throttle: recur WG0 publishes progress=t (clamped on poison);
//   pregate waits until t <= progress+510.  Deadlock-free: 256 WGs all
//   co-resident (66.5 KB LDS -> 1 WG/CU, 1024 waves << capacity).
//
// Fallbacks: R11 chunked two-phase if ws < 134.5 MB; R4 single kernel if
// ws < 4.4 MB.

#define T_STEPS 1024
#define BATCH   32
#define DIN     512
#define H       512
#define NWG     64
#define NPRE    192
#define HC      8
#define XSTRIDE 520        // f16 elems; 1040B row = bank offset 4 -> 2-way max (free)
#define GSTRIDE 34         // padded f32 row stride (R4 fallback only)
#define RECS_PER_PARITY 8192   // 16 kk * 512   (R4 record format)
#define RING_SLOTS 512

typedef _Float16 half8  __attribute__((ext_vector_type(8)));
typedef _Float16 half4v __attribute__((ext_vector_type(4)));
typedef float    f32x4  __attribute__((ext_vector_type(4)));
typedef unsigned int u32;
typedef unsigned long long u64;
typedef u32 u32x4 __attribute__((ext_vector_type(4)));

#define AT_LD_U64(p)   __hip_atomic_load((const u64*)(p), __ATOMIC_RELAXED, __HIP_MEMORY_SCOPE_AGENT)
#define AT_ST_U64(p,v) __hip_atomic_store((u64*)(p), (v), __ATOMIC_RELAXED, __HIP_MEMORY_SCOPE_AGENT)

__device__ __forceinline__ float sigmoidf_(float x) {
    return 1.0f / (1.0f + __expf(-x));
}
__device__ __forceinline__ float tanhf_(float x) {
    return 1.0f - 2.0f / (1.0f + __expf(2.0f * x));
}

// ======================= fused kernel ===================================
__global__ __launch_bounds__(256, 1) void lstm_fused(
    const float* __restrict__ x,
    const float* __restrict__ init_states,
    const float* __restrict__ Wi, const float* __restrict__ Wf,
    const float* __restrict__ Wc, const float* __restrict__ Wo,
    const float* __restrict__ Ui, const float* __restrict__ Uf,
    const float* __restrict__ Uc, const float* __restrict__ Uo,
    const float* __restrict__ bi, const float* __restrict__ bf,
    const float* __restrict__ bc, const float* __restrict__ bo,
    float* __restrict__ out,
    float* __restrict__ preg,     // ring: [512][4][512][32] f32
    u64*   __restrict__ hrec,     // 2 parities x 8192 records
    u32*   __restrict__ pflag,    // [1024][32] ready flags (exact-match t+1)
    int*   __restrict__ progress) // recur WG0 step watermark
{
    __shared__ __align__(16) char smem[2 * BATCH * XSTRIDE * 2];  // 66,560 B

    const int tid  = threadIdx.x;
    const int wg   = blockIdx.x;
    const int lane = tid & 63;
    const int wave = tid >> 6;

    if (wg < NWG) {
        // ================= recur role (R11 verbatim protocol) ============
        // LDS layout: [par][mt][kk][lane][4] u32  (32 KB of the 66.5 KB)
        u32* share = (u32*)smem;
        auto shp = [&](int par, int mtv, int kk, int ln) -> u32* {
            return &share[(((par * 2 + mtv) * 16 + kk) * 64 + ln) * 4];
        };

        const int mt = wave & 1;
        const int nt = wave >> 1;
        const int n_local = lane & 15;
        const int kq = lane >> 4;
        const int row = mt * 16 + n_local;      // A-frag batch row (poll id)

        const int gi   = n_local >> 2;          // gate of this lane's n-col
        const int cl   = n_local & 3;
        const int ejl  = nt * 4 + cl;           // local h-col 0..7
        const int wcol = wg * HC + ejl;
        const int eb   = mt * 16 + kq * 4 + gi; // post-transpose owned batch
        const int ecol = wcol;

        float c_state = init_states[BATCH * H + eb * H + ecol];
        const int widx = (wg >> 2) * 512 + (ejl >> 1) * 128 + eb * 4 + (wg & 3);

        // publish h0 (epoch 1, parity 0)
        {
            _Float16 h0 = (_Float16)init_states[eb * H + ecol];
            u32 hu  = (u32)__builtin_bit_cast(unsigned short, h0);
            u32 oth = __shfl_down(hu, 1);
            if ((lane & 1) == 0)
                AT_ST_U64(&hrec[widx], ((u64)1u << 32) | (u64)(hu | (oth << 16)));
        }

        // one-time: U B-fragments
        const float* Umat = (gi == 0) ? Ui : (gi == 1) ? Uf : (gi == 2) ? Uc : Uo;
        half8 bfrag[16];
        #pragma unroll
        for (int kk = 0; kk < 16; ++kk) {
            #pragma unroll
            for (int jj = 0; jj < 8; ++jj) {
                int k = kk * 32 + kq * 8 + jj;
                bfrag[kk][jj] = (_Float16)Umat[k * H + wcol];
            }
        }

        const size_t pgbase =
            ((size_t)gi * 512 + wcol) * 32 + mt * 16 + kq * 4;   // even
        const u64* pregq = (const u64*)preg;

        auto waitpreg = [&](int t) {
            const u32 tgt = (u32)(t + 1);
            const u32* fp = pflag + (size_t)t * 32;
            unsigned sp = 0;
            for (;;) {
                u32 v = (lane < 32)
                    ? __hip_atomic_load(&fp[lane], __ATOMIC_RELAXED,
                                        __HIP_MEMORY_SCOPE_AGENT)
                    : tgt;
                if (__all(v == tgt)) break;
                if (++sp > 2000000u) break;    // safety valve
            }
        };
        auto ldpg = [&](int t) -> f32x4 {
            size_t qi = (((size_t)(t & (RING_SLOTS - 1))) * 65536 + pgbase) >> 1;
            union { u64 q[2]; f32x4 v; } u;
            u.q[0] = AT_LD_U64(&pregq[qi]);
            u.q[1] = AT_LD_U64(&pregq[qi + 1]);
            return u.v;
        };

        waitpreg(0);
        f32x4 pg = ldpg(0);

        const int ridx_base = row * 4 + kq;
        const int kk0 = nt * 8;
        const bool q0 = (lane >> 2) & 1;
        const bool q1 = (lane >> 3) & 1;

        for (int t = 0; t < T_STEPS; ++t) {
            const u64* rb = hrec + (size_t)(t & 1) * RECS_PER_PARITY;
            const u32 target = (u32)(t + 1);
            const int par = t & 1;

            // ---- poll OWN 32 records (branch-free full reload) ----------
            u64 rec[32];
            unsigned spins = 0;
            for (;;) {
                #pragma unroll
                for (int kk2 = 0; kk2 < 8; ++kk2) {
                    #pragma unroll
                    for (int s = 0; s < 4; ++s)
                        rec[kk2 * 4 + s] =
                            AT_LD_U64(&rb[(kk0 + kk2) * 512 + s * 128 + ridx_base]);
                }
                int ok = 1;
                #pragma unroll
                for (int i = 0; i < 32; ++i)
                    ok &= ((u32)(rec[i] >> 32) == target);
                if (__all(ok)) break;
                if (++spins > 300000u) break;   // safety valve
            }

            // ---- publish own payloads to LDS (parity bank) --------------
            #pragma unroll
            for (int kk2 = 0; kk2 < 8; ++kk2) {
                u32x4 v = { (u32)rec[kk2 * 4 + 0], (u32)rec[kk2 * 4 + 1],
                            (u32)rec[kk2 * 4 + 2], (u32)rec[kk2 * 4 + 3] };
                *(u32x4*)shp(par, mt, kk0 + kk2, lane) = v;
            }

            // prefetch next step's pre-gate (ready-gated; overlaps barrier)
            f32x4 pgn = pg;
            if (t + 1 < T_STEPS) {
                waitpreg(t + 1);
                pgn = ldpg(t + 1);
            }

            __syncthreads();   // the ONLY barrier per step

            // ---- read all 16 kk A-frag payloads from LDS ----------------
            u32x4 au[16];
            #pragma unroll
            for (int kk = 0; kk < 16; ++kk)
                au[kk] = *(const u32x4*)shp(par, mt, kk, lane);

            // ---- h-half matmul; acc starts at pre-gate (x@W + b) -------
            f32x4 acc  = pg;
            f32x4 acc2 = {0.f, 0.f, 0.f, 0.f};
            #pragma unroll
            for (int kk = 0; kk < 16; kk += 2) {
                union { u32x4 v; half8 h; } a0, a1;
                a0.v = au[kk];
                a1.v = au[kk + 1];
                acc  = __builtin_amdgcn_mfma_f32_16x16x32_f16(a0.h, bfrag[kk],     acc,  0, 0, 0);
                acc2 = __builtin_amdgcn_mfma_f32_16x16x32_f16(a1.h, bfrag[kk + 1], acc2, 0, 0, 0);
            }
            float a0v = acc[0] + acc2[0];
            float a1v = acc[1] + acc2[1];
            float a2v = acc[2] + acc2[2];
            float a3v = acc[3] + acc2[3];

            // ---- in-wave 4x4 transpose (gate axis <-> r axis) -----------
            float t0_ = __shfl_xor(a1v, 4);
            float t1_ = __shfl_xor(a0v, 4);
            float t2_ = __shfl_xor(a3v, 4);
            float t3_ = __shfl_xor(a2v, 4);
            float b0 = q0 ? t0_ : a0v;
            float b1 = q0 ? a1v : t1_;
            float b2 = q0 ? t2_ : a2v;
            float b3 = q0 ? a3v : t3_;
            float u0 = __shfl_xor(b2, 8);
            float u1 = __shfl_xor(b3, 8);
            float u2 = __shfl_xor(b0, 8);
            float u3 = __shfl_xor(b1, 8);
            float pi  = q1 ? u0 : b0;
            float pf  = q1 ? u1 : b1;
            float pgg = q1 ? b2 : u2;
            float po  = q1 ? b3 : u3;

            // ---- gates + state update + immediate publish ---------------
            float ig = sigmoidf_(pi);
            float fg = sigmoidf_(pf);
            float gg = tanhf_(pgg);
            float og = sigmoidf_(po);
            c_state  = fg * c_state + ig * gg;
            float h_val = og * tanhf_(c_state);

            if (t + 1 < T_STEPS) {
                _Float16 hh = (_Float16)h_val;
                u32 hu  = (u32)__builtin_bit_cast(unsigned short, hh);
                u32 oth = __shfl_down(hu, 1);
                if ((lane & 1) == 0) {
                    AT_ST_U64(&hrec[(size_t)((t + 1) & 1) * RECS_PER_PARITY + widx],
                              ((u64)(u32)(t + 2) << 32) | (u64)(hu | (oth << 16)));
                }
            }

            // off-critical-path tail
            out[((size_t)eb * T_STEPS + t) * H + ecol] = h_val;
            if (wg == 0 && tid == 0)
                __hip_atomic_store(progress, t, __ATOMIC_RELAXED,
                                   __HIP_MEMORY_SCOPE_AGENT);
            pg = pgn;
        }
    } else {
        // ================= pregate role =================================
        _Float16* xbuf = (_Float16*)smem;   // [2][BATCH][XSTRIDE]

        const int g2  = wg - NWG;           // 0..191
        const int cb  = g2 & 31;            // h-cols [cb*16, cb*16+16)
        const int tsl = g2 >> 5;            // t-slice 0..5: t = tsl + 6k
        const int mt  = wave & 1;           // batch half
        const int gp  = wave >> 1;          // gate pair 0..1 (4 waves)
        const int n_local = lane & 15;
        const int kq  = lane >> 4;
        const int row = mt * 16 + n_local;
        const int hcol = cb * 16 + n_local;

        const float* W0  = (gp == 0) ? Wi : Wc;
        const float* W1  = (gp == 0) ? Wf : Wo;
        const float* b0p = (gp == 0) ? bi : bc;
        const float* b1p = (gp == 0) ? bf : bo;
        const float bv0 = b0p[hcol];
        const float bv1 = b1p[hcol];

        half8 bw0[16], bw1[16];             // 128 VGPRs
        #pragma unroll
        for (int kk = 0; kk < 16; ++kk) {
            #pragma unroll
            for (int jj = 0; jj < 8; ++jj) {
                int k = kk * 32 + kq * 8 + jj;
                bw0[kk][jj] = (_Float16)W0[k * H + hcol];
                bw1[kk][jj] = (_Float16)W1[k * H + hcol];
            }
        }

        // x staging (f32 -> f16), 256-thread version (R4)
        auto stage = [&](int t, int buf) {
            const int sb = tid >> 3;
            const int so = (tid & 7) * 4;
            const float* xr = x + ((size_t)sb * T_STEPS + t) * DIN;
            _Float16* xb = &xbuf[buf * (BATCH * XSTRIDE)];
            #pragma unroll
            for (int q = 0; q < 16; ++q) {
                int colq = so + q * 32;
                float4 v = *(const float4*)(xr + colq);
                half4v hv = { (_Float16)v.x, (_Float16)v.y,
                              (_Float16)v.z, (_Float16)v.w };
                *(half4v*)&xb[sb * XSTRIDE + colq] = hv;
            }
        };

        stage(tsl, 0);
        stage(tsl + 6, 1);
        __syncthreads();

        u64* pregq = (u64*)preg;

        for (int k = 0, t = tsl; t < T_STEPS; ++k, t += 6) {
            // ring throttle: old content of slot t&511 is preg[t-512],
            // consumed by recur during its step t-513 -> need progress >=
            // t-510 (margin).  Poisoned/unwritten progress clamps to 0.
            if (t > 510) {
                unsigned sp = 0;
                for (;;) {
                    int p = __hip_atomic_load(progress, __ATOMIC_RELAXED,
                                              __HIP_MEMORY_SCOPE_AGENT);
                    if (p < 0 || p >= T_STEPS) p = 0;
                    if (t <= p + 510) break;
                    if (++sp > 4000000u) break;   // safety valve
                    __builtin_amdgcn_s_sleep(8);
                }
            }

            const _Float16* xr2 =
                &xbuf[(k & 1) * (BATCH * XSTRIDE) + row * XSTRIDE + kq * 8];
            f32x4 a0 = {0.f,0.f,0.f,0.f}, a1 = {0.f,0.f,0.f,0.f};
            f32x4 a2 = {0.f,0.f,0.f,0.f}, a3 = {0.f,0.f,0.f,0.f};
            #pragma unroll
            for (int kk = 0; kk < 16; kk += 2) {
                half8 v0 = *(const half8*)(xr2 + kk * 32);
                half8 v1 = *(const half8*)(xr2 + (kk + 1) * 32);
                a0 = __builtin_amdgcn_mfma_f32_16x16x32_f16(v0, bw0[kk],     a0, 0, 0, 0);
                a1 = __builtin_amdgcn_mfma_f32_16x16x32_f16(v0, bw1[kk],     a1, 0, 0, 0);
                a2 = __builtin_amdgcn_mfma_f32_16x16x32_f16(v1, bw0[kk + 1], a2, 0, 0, 0);
                a3 = __builtin_amdgcn_mfma_f32_16x16x32_f16(v1, bw1[kk + 1], a3, 0, 0, 0);
            }

            // store both gates (agent-scope atomics -> MALL, cross-XCD safe)
            const int slot = t & (RING_SLOTS - 1);
            {
                union { f32x4 v; u64 q[2]; } u;
                #pragma unroll
                for (int r = 0; r < 4; ++r) u.v[r] = a0[r] + a2[r] + bv0;
                size_t base = (((size_t)slot * 4 + gp * 2) * 512 + hcol) * 32
                              + mt * 16 + kq * 4;
                AT_ST_U64(&pregq[base >> 1], u.q[0]);
                AT_ST_U64(&pregq[(base >> 1) + 1], u.q[1]);
                #pragma unroll
                for (int r = 0; r < 4; ++r) u.v[r] = a1[r] + a3[r] + bv1;
                base += (size_t)512 * 32;
                AT_ST_U64(&pregq[base >> 1], u.q[0]);
                AT_ST_U64(&pregq[(base >> 1) + 1], u.q[1]);
            }

            __syncthreads();   // drains all waves' stores (vmcnt0 + barrier)
            if (tid == 0)
                __hip_atomic_store(&pflag[(size_t)t * 32 + cb], (u32)(t + 1),
                                   __ATOMIC_RELEASE, __HIP_MEMORY_SCOPE_AGENT);
            if (t + 12 < T_STEPS) stage(t + 12, k & 1);
        }
    }
}

// ======================= chunked fallback (R11) =========================
__global__ __launch_bounds__(512, 1) void lstm_pregate(
    const float* __restrict__ x,
    const float* __restrict__ Wi, const float* __restrict__ Wf,
    const float* __restrict__ Wc, const float* __restrict__ Wo,
    const float* __restrict__ bi, const float* __restrict__ bf,
    const float* __restrict__ bc, const float* __restrict__ bo,
    float* __restrict__ preg, int t0, int tc)
{
    __shared__ _Float16 xbuf[2 * BATCH * XSTRIDE];

    const int tid  = threadIdx.x;
    const int wg   = blockIdx.x;
    const int cb   = wg & 31;
    const int tq   = wg >> 5;
    const int tcq  = tc >> 3;
    const int tb   = t0 + tq * tcq;
    const int lane = tid & 63;
    const int wave = tid >> 6;
    const int mt   = wave & 1;
    const int gsel = wave >> 1;        // 8 waves REQUIRED
    const int n_local = lane & 15;
    const int kq   = lane >> 4;
    const int row  = mt * 16 + n_local;
    const int hcol = cb * 16 + n_local;

    const float* Wmat = (gsel == 0) ? Wi : (gsel == 1) ? Wf : (gsel == 2) ? Wc : Wo;
    const float* bvec = (gsel == 0) ? bi : (gsel == 1) ? bf : (gsel == 2) ? bc : bo;
    const float bv = bvec[hcol];

    half8 bfrag[16];
    #pragma unroll
    for (int kk = 0; kk < 16; ++kk) {
        #pragma unroll
        for (int jj = 0; jj < 8; ++jj) {
            int k = kk * 32 + kq * 8 + jj;
            bfrag[kk][jj] = (_Float16)Wmat[k * H + hcol];
        }
    }

    auto stage = [&](int t, int buf) {
        const int sb = tid >> 4;
        const int so = (tid & 15) * 4;
        const float* xr = x + ((size_t)sb * T_STEPS + t) * DIN;
        _Float16* xb = &xbuf[buf * (BATCH * XSTRIDE)];
        #pragma unroll
        for (int q = 0; q < 8; ++q) {
            int colq = so + q * 64;
            float4 v = *(const float4*)(xr + colq);
            half4v hv = { (_Float16)v.x, (_Float16)v.y,
                          (_Float16)v.z, (_Float16)v.w };
            *(half4v*)&xb[sb * XSTRIDE + colq] = hv;
        }
    };

    stage(tb, 0);
    stage(tb + 1, 1);
    __syncthreads();

    for (int lt = 0; lt < tcq; ++lt) {
        f32x4 a0 = {0.f,0.f,0.f,0.f};
        f32x4 a1 = {0.f,0.f,0.f,0.f};
        const _Float16* xr2 =
            &xbuf[(lt & 1) * (BATCH * XSTRIDE) + row * XSTRIDE + kq * 8];
        #pragma unroll
        for (int kk = 0; kk < 16; kk += 2) {
            half8 v0 = *(const half8*)(xr2 + kk * 32);
            half8 v1 = *(const half8*)(xr2 + (kk + 1) * 32);
            a0 = __builtin_amdgcn_mfma_f32_16x16x32_f16(v0, bfrag[kk],     a0, 0, 0, 0);
            a1 = __builtin_amdgcn_mfma_f32_16x16x32_f16(v1, bfrag[kk + 1], a1, 0, 0, 0);
        }
        f32x4 aw;
        #pragma unroll
        for (int r = 0; r < 4; ++r) aw[r] = a0[r] + a1[r] + bv;

        const size_t base =
            (((size_t)(tb - t0 + lt) * 4 + gsel) * 512 + hcol) * 32
            + mt * 16 + kq * 4;
        *(f32x4*)&preg[base] = aw;

        __syncthreads();
        if (lt + 2 < tcq) stage(tb + lt + 2, lt & 1);
    }
}

__global__ __launch_bounds__(256, 1) void lstm_recur(
    const float* __restrict__ init_states,
    const float* __restrict__ Ui, const float* __restrict__ Uf,
    const float* __restrict__ Uc, const float* __restrict__ Uo,
    const float* __restrict__ preg,
    float* __restrict__ out,
    u64* __restrict__ hrec,
    float* __restrict__ cst,
    int t0, int tc)
{
    __shared__ u32 share[2][2][16][64][4];

    const int tid  = threadIdx.x;
    const int wg   = blockIdx.x;
    const int lane = tid & 63;
    const int wave = tid >> 6;
    const int mt   = wave & 1;
    const int nt   = wave >> 1;
    const int n_local = lane & 15;
    const int kq   = lane >> 4;
    const int row  = mt * 16 + n_local;

    const int gi   = n_local >> 2;
    const int cl   = n_local & 3;
    const int ejl  = nt * 4 + cl;
    const int wcol = wg * HC + ejl;
    const int eb   = mt * 16 + kq * 4 + gi;
    const int ecol = wcol;

    float c_state = (t0 == 0) ? init_states[BATCH * H + eb * H + ecol]
                              : cst[eb * H + ecol];

    const int widx = (wg >> 2) * 512 + (ejl >> 1) * 128 + eb * 4 + (wg & 3);

    if (t0 == 0) {
        _Float16 h0 = (_Float16)init_states[eb * H + ecol];
        u32 hu  = (u32)__builtin_bit_cast(unsigned short, h0);
        u32 oth = __shfl_down(hu, 1);
        if ((lane & 1) == 0)
            AT_ST_U64(&hrec[widx], ((u64)1u << 32) | (u64)(hu | (oth << 16)));
    }

    const float* Umat = (gi == 0) ? Ui : (gi == 1) ? Uf : (gi == 2) ? Uc : Uo;
    half8 bfrag[16];
    #pragma unroll
    for (int kk = 0; kk < 16; ++kk) {
        #pragma unroll
        for (int jj = 0; jj < 8; ++jj) {
            int k = kk * 32 + kq * 8 + jj;
            bfrag[kk][jj] = (_Float16)Umat[k * H + wcol];
        }
    }

    const size_t pgbase =
        ((size_t)gi * 512 + wcol) * 32 + mt * 16 + kq * 4;
    f32x4 pg = *(const f32x4*)&preg[pgbase];

    const int ridx_base = row * 4 + kq;
    const int kk0 = nt * 8;
    const bool q0 = (lane >> 2) & 1;
    const bool q1 = (lane >> 3) & 1;

    for (int lt = 0; lt < tc; ++lt) {
        const int gt = t0 + lt;
        const u64* rb = hrec + (size_t)(gt & 1) * RECS_PER_PARITY;
        const u32 target = (u32)(gt + 1);
        const int par = gt & 1;

        u64 rec[32];
        unsigned spins = 0;
        for (;;) {
            #pragma unroll
            for (int kk2 = 0; kk2 < 8; ++kk2) {
                #pragma unroll
                for (int s = 0; s < 4; ++s)
                    rec[kk2 * 4 + s] =
                        AT_LD_U64(&rb[(kk0 + kk2) * 512 + s * 128 + ridx_base]);
            }
            int ok = 1;
            #pragma unroll
            for (int i = 0; i < 32; ++i)
                ok &= ((u32)(rec[i] >> 32) == target);
            if (__all(ok)) break;
            if (++spins > 300000u) break;
        }

        #pragma unroll
        for (int kk2 = 0; kk2 < 8; ++kk2) {
            u32x4 v = { (u32)rec[kk2 * 4 + 0], (u32)rec[kk2 * 4 + 1],
                        (u32)rec[kk2 * 4 + 2], (u32)rec[kk2 * 4 + 3] };
            *(u32x4*)&share[par][mt][kk0 + kk2][lane][0] = v;
        }

        f32x4 pgn = pg;
        if (lt + 1 < tc)
            pgn = *(const f32x4*)&preg[(size_t)(lt + 1) * 65536 + pgbase];

        __syncthreads();

        u32x4 au[16];
        #pragma unroll
        for (int kk = 0; kk < 16; ++kk)
            au[kk] = *(const u32x4*)&share[par][mt][kk][lane][0];

        f32x4 acc  = pg;
        f32x4 acc2 = {0.f, 0.f, 0.f, 0.f};
        #pragma unroll
        for (int kk = 0; kk < 16; kk += 2) {
            union { u32x4 v; half8 h; } a0, a1;
            a0.v = au[kk];
            a1.v = au[kk + 1];
            acc  = __builtin_amdgcn_mfma_f32_16x16x32_f16(a0.h, bfrag[kk],     acc,  0, 0, 0);
            acc2 = __builtin_amdgcn_mfma_f32_16x16x32_f16(a1.h, bfrag[kk + 1], acc2, 0, 0, 0);
        }
        float a0v = acc[0] + acc2[0];
        float a1v = acc[1] + acc2[1];
        float a2v = acc[2] + acc2[2];
        float a3v = acc[3] + acc2[3];

        float t0_ = __shfl_xor(a1v, 4);
        float t1_ = __shfl_xor(a0v, 4);
        float t2_ = __shfl_xor(a3v, 4);
        float t3_ = __shfl_xor(a2v, 4);
        float b0 = q0 ? t0_ : a0v;
        float b1 = q0 ? a1v : t1_;
        float b2 = q0 ? t2_ : a2v;
        float b3 = q0 ? a3v : t3_;
        float u0 = __shfl_xor(b2, 8);
        float u1 = __shfl_xor(b3, 8);
        float u2 = __shfl_xor(b0, 8);
        float u3 = __shfl_xor(b1, 8);
        float pi  = q1 ? u0 : b0;
        float pf  = q1 ? u1 : b1;
        float pgg = q1 ? b2 : u2;
        float po  = q1 ? b3 : u3;

        float ig = sigmoidf_(pi);
        float fg = sigmoidf_(pf);
        float gg = tanhf_(pgg);
        float og = sigmoidf_(po);
        c_state  = fg * c_state + ig * gg;
        float h_val = og * tanhf_(c_state);

        if (gt + 1 < T_STEPS) {
            _Float16 hh = (_Float16)h_val;
            u32 hu  = (u32)__builtin_bit_cast(unsigned short, hh);
            u32 oth = __shfl_down(hu, 1);
            if ((lane & 1) == 0) {
                AT_ST_U64(&hrec[(size_t)((gt + 1) & 1) * RECS_PER_PARITY + widx],
                          ((u64)(u32)(gt + 2) << 32) | (u64)(hu | (oth << 16)));
            }
        }

        out[((size_t)eb * T_STEPS + gt) * H + ecol] = h_val;
        pg = pgn;
    }

    cst[eb * H + ecol] = c_state;
}

// ======================= fallback: R4 single kernel =====================
__global__ __launch_bounds__(256, 1) void lstm_persistent_fb(
    const float* __restrict__ x,
    const float* __restrict__ init_states,
    const float* __restrict__ Wi, const float* __restrict__ Ui, const float* __restrict__ bi,
    const float* __restrict__ Wf, const float* __restrict__ Uf, const float* __restrict__ bf,
    const float* __restrict__ Wc, const float* __restrict__ Uc, const float* __restrict__ bc,
    const float* __restrict__ Wo, const float* __restrict__ Uo, const float* __restrict__ bo,
    float* __restrict__ out,
    u64* __restrict__ hrec)
{
    __shared__ _Float16 xbuf[2 * BATCH * XSTRIDE];
    __shared__ float    gbuf[2 * BATCH * GSTRIDE];

    const int tid  = threadIdx.x;
    const int wg   = blockIdx.x;
    const int lane = tid & 63;
    const int wave = tid >> 6;
    const int mt   = wave & 1;
    const int nt   = wave >> 1;
    const int row  = mt * 16 + (lane & 15);
    const int kq   = lane >> 4;

    const int eb   = tid >> 3;
    const int ej   = tid & 7;
    const int ecol = wg * HC + ej;

    float c_state = init_states[BATCH * H + eb * H + ecol];
    {
        _Float16 h0 = (_Float16)init_states[eb * H + ecol];
        u32 hu  = (u32)__builtin_bit_cast(unsigned short, h0);
        u32 oth = __shfl_down(hu, 1);
        if ((tid & 1) == 0) {
            const int ridx = (wg >> 2) * 512 + (ej >> 1) * 128 + eb * 4 + (wg & 3);
            AT_ST_U64(&hrec[ridx], ((u64)1u << 32) | (u64)(hu | (oth << 16)));
        }
    }

    const int n_local = lane & 15;
    const int gi   = nt * 2 + (n_local >> 3);
    const int wcol = wg * HC + (n_local & 7);
    const float* Wmat = (gi == 0) ? Wi : (gi == 1) ? Wf : (gi == 2) ? Wc : Wo;
    const float* Umat = (gi == 0) ? Ui : (gi == 1) ? Uf : (gi == 2) ? Uc : Uo;

    half8 bfrag[32];
    #pragma unroll
    for (int kk = 0; kk < 16; ++kk) {
        #pragma unroll
        for (int jj = 0; jj < 8; ++jj) {
            int k = kk * 32 + kq * 8 + jj;
            bfrag[kk][jj]      = (_Float16)Wmat[k * H + wcol];
            bfrag[16 + kk][jj] = (_Float16)Umat[k * H + wcol];
        }
    }

    const float bi_v = bi[ecol], bf_v = bf[ecol], bc_v = bc[ecol], bo_v = bo[ecol];

    auto stage = [&](int t, int buf) {
        const int sb = tid >> 3;
        const int so = (tid & 7) * 4;
        const float* xr = x + ((size_t)sb * T_STEPS + t) * DIN;
        _Float16* xb = &xbuf[buf * (BATCH * XSTRIDE)];
        #pragma unroll
        for (int q = 0; q < 16; ++q) {
            int colq = so + q * 32;
            float4 v = *(const float4*)(xr + colq);
            half4v hv = { (_Float16)v.x, (_Float16)v.y,
                          (_Float16)v.z, (_Float16)v.w };
            *(half4v*)&xb[sb * XSTRIDE + colq] = hv;
        }
    };
    auto xmm = [&](int buf) -> f32x4 {
        f32x4 ax  = {0.f, 0.f, 0.f, 0.f};
        f32x4 ax2 = {0.f, 0.f, 0.f, 0.f};
        const _Float16* xr2 = &xbuf[buf * (BATCH * XSTRIDE) + row * XSTRIDE + kq * 8];
        #pragma unroll
        for (int kk = 0; kk < 16; kk += 2) {
            half8 a0 = *(const half8*)(xr2 + kk * 32);
            half8 a1 = *(const half8*)(xr2 + (kk + 1) * 32);
            ax  = __builtin_amdgcn_mfma_f32_16x16x32_f16(a0, bfrag[kk],     ax,  0, 0, 0);
            ax2 = __builtin_amdgcn_mfma_f32_16x16x32_f16(a1, bfrag[kk + 1], ax2, 0, 0, 0);
        }
        #pragma unroll
        for (int r = 0; r < 4; ++r) ax[r] += ax2[r];
        return ax;
    };

    stage(0, 0);
    stage(1, 1);
    __syncthreads();
    f32x4 acc_x = xmm(0);

    const int ridx_base = row * 4 + kq;
    const int widx = (wg >> 2) * 512 + (ej >> 1) * 128 + eb * 4 + (wg & 3);

    for (int t = 0; t < T_STEPS; ++t) {
        const u64* rb = hrec + (size_t)(t & 1) * RECS_PER_PARITY;
        const u32 target = (u32)(t + 1);

        u64 rec[64];
        unsigned spins = 0;
        for (;;) {
            #pragma unroll
            for (int kk = 0; kk < 16; ++kk) {
                #pragma unroll
                for (int s = 0; s < 4; ++s)
                    rec[kk * 4 + s] = AT_LD_U64(&rb[kk * 512 + s * 128 + ridx_base]);
            }
            int ok = 1;
            #pragma unroll
            for (int i = 0; i < 64; ++i)
                ok &= ((u32)(rec[i] >> 32) == target);
            if (__all(ok)) break;
            if (++spins > 300000u) break;
        }

        float* gb = &gbuf[(t & 1) * (BATCH * GSTRIDE)];
        {
            f32x4 acc  = acc_x;
            f32x4 acc2 = {0.f, 0.f, 0.f, 0.f};
            #pragma unroll
            for (int kk = 0; kk < 16; kk += 2) {
                union { u32 d[4]; half8 h; } a0, a1;
                #pragma unroll
                for (int s = 0; s < 4; ++s) {
                    a0.d[s] = (u32)rec[kk * 4 + s];
                    a1.d[s] = (u32)rec[(kk + 1) * 4 + s];
                }
                acc  = __builtin_amdgcn_mfma_f32_16x16x32_f16(a0.h, bfrag[16 + kk],     acc,  0, 0, 0);
                acc2 = __builtin_amdgcn_mfma_f32_16x16x32_f16(a1.h, bfrag[16 + kk + 1], acc2, 0, 0, 0);
            }
            #pragma unroll
            for (int r = 0; r < 4; ++r) {
                gb[(mt * 16 + kq * 4 + r) * GSTRIDE + nt * 16 + n_local] =
                    acc[r] + acc2[r];
            }
        }
        __syncthreads();

        float h_val;
        {
            float pi = gb[eb * GSTRIDE + ej]      + bi_v;
            float pf = gb[eb * GSTRIDE + 8 + ej]  + bf_v;
            float pg = gb[eb * GSTRIDE + 16 + ej] + bc_v;
            float po = gb[eb * GSTRIDE + 24 + ej] + bo_v;
            float ig = sigmoidf_(pi);
            float fg = sigmoidf_(pf);
            float gg = tanhf_(pg);
            float og = sigmoidf_(po);
            c_state  = fg * c_state + ig * gg;
            h_val    = og * tanhf_(c_state);

            if (t + 1 < T_STEPS) {
                _Float16 hh = (_Float16)h_val;
                u32 hu  = (u32)__builtin_bit_cast(unsigned short, hh);
                u32 oth = __shfl_down(hu, 1);
                if ((tid & 1) == 0) {
                    AT_ST_U64(&hrec[(size_t)((t + 1) & 1) * RECS_PER_PARITY + widx],
                              ((u64)(u32)(t + 2) << 32) | (u64)(hu | (oth << 16)));
                }
            }
        }

        out[((size_t)eb * T_STEPS + t) * H + ecol] = h_val;
        if (t + 1 < T_STEPS) {
            acc_x = xmm((t + 1) & 1);
            if (t + 2 < T_STEPS) stage(t + 2, t & 1);
        }
    }
}

// ======================= launcher ======================================
extern "C" void kernel_launch(void* const* d_in, const int* in_sizes, int n_in,
                              void* d_out, int out_size, void* d_ws, size_t ws_size,
                              hipStream_t stream) {
    const float* x           = (const float*)d_in[0];
    const float* init_states = (const float*)d_in[1];
    const float* Wi = (const float*)d_in[2];
    const float* Ui = (const float*)d_in[3];
    const float* bi = (const float*)d_in[4];
    const float* Wf = (const float*)d_in[5];
    const float* Uf = (const float*)d_in[6];
    const float* bf = (const float*)d_in[7];
    const float* Wc = (const float*)d_in[8];
    const float* Uc = (const float*)d_in[9];
    const float* bc = (const float*)d_in[10];
    const float* Wo = (const float*)d_in[11];
    const float* Uo = (const float*)d_in[12];
    const float* bo = (const float*)d_in[13];
    float* out = (float*)d_out;

    const size_t RING_BYTES  = (size_t)RING_SLOTS * 65536 * 4;   // 134,217,728
    const size_t HREC_BYTES  = (size_t)2 * RECS_PER_PARITY * 8;  // 128 KB
    const size_t PFLAG_BYTES = (size_t)T_STEPS * 32 * 4;         // 128 KB
    const size_t PROG_BYTES  = 64;
    const size_t CST_BYTES   = (size_t)BATCH * H * 4;            //  64 KB

    if (ws_size >= RING_BYTES + HREC_BYTES + PFLAG_BYTES + PROG_BYTES) {
        // -------- fused single-launch path --------
        float* preg = (float*)d_ws;
        u64*   hrec = (u64*)((char*)d_ws + RING_BYTES);
        u32*   pflag = (u32*)((char*)d_ws + RING_BYTES + HREC_BYTES);
        int*   progress = (int*)((char*)d_ws + RING_BYTES + HREC_BYTES + PFLAG_BYTES);

        lstm_fused<<<dim3(NWG + NPRE), dim3(256), 0, stream>>>(
            x, init_states, Wi, Wf, Wc, Wo, Ui, Uf, Uc, Uo,
            bi, bf, bc, bo, out, preg, hrec, pflag, progress);
        return;
    }

    // -------- chunked two-phase fallback (R11) --------
    static const int cands[] = {512, 256, 128, 64, 32, 16};
    int tc = 0;
    size_t preg_bytes = 0;
    for (int i = 0; i < 6; ++i) {
        size_t pb = (size_t)cands[i] * 2048 * 32 * 4;
        if (ws_size >= pb + HREC_BYTES + CST_BYTES) { tc = cands[i]; preg_bytes = pb; break; }
    }

    if (tc > 0) {
        float* preg = (float*)d_ws;
        u64*   hrec = (u64*)((char*)d_ws + preg_bytes);
        float* cst  = (float*)((char*)d_ws + preg_bytes + HREC_BYTES);

        const int nchunks = T_STEPS / tc;
        for (int c = 0; c < nchunks; ++c) {
            lstm_pregate<<<dim3(256), dim3(512), 0, stream>>>(
                x, Wi, Wf, Wc, Wo, bi, bf, bc, bo, preg, c * tc, tc);
            lstm_recur<<<dim3(NWG), dim3(256), 0, stream>>>(
                init_states, Ui, Uf, Uc, Uo, preg, out, hrec, cst, c * tc, tc);
        }
    } else {
        u64* hrec = (u64*)d_ws;
        lstm_persistent_fb<<<dim3(NWG), dim3(256), 0, stream>>>(
            x, init_states, Wi, Ui, bi, Wf, Uf, bf, Wc, Uc, bc, Wo, Uo, bo,
            out, hrec);
    }
}

// Round 10
// 3070.172 us; speedup vs baseline: 1.3151x; 1.3151x over previous
//
#include <hip/hip_runtime.h>

// Single-launch fused LSTM for MI355X.  B=32, T=1024, D_IN=512, H=512.
//
// R14 = R13 with the producer->consumer channel redesigned after R13's
// falsifier fired (3980 us > 3100; FETCH 742MB/WRITE 855MB = 134MB preg
// ring spilled L3, and waitpreg->ldpg added 2 serialized MALL RTTs/step).
//
// Fix (session invariant: THE POLLING LOAD MUST BE THE DATA LOAD):
//   pre-gate values are SELF-VALIDATING 8B records {epoch(t+1)|2xf16},
//   2 per consumer lane per step, in a 128-slot ring (32 MB, L3-resident,
//   layout = consumer read order).  Consumer folds them into the existing
//   h-poll: 34 loads, SAME target epoch, one __all.  pflag/waitpreg/ldpg
//   deleted -> zero added critical-path RTTs.  Producers pack f32x4 ->
//   2 records and fire 4 relaxed agent stores/lane (off-path; no ordering
//   needed - records are individually valid by 8B store atomicity).
//   Ring throttle: producer t <= progress+120; h-lockstep bounds consumer
//   skew to 1 step so the overwritten slot (distance >=122) is never live.
//   f16 pre-gate rounding ~5e-4 abs; budget 0.0199, current 0.0039.
//
//   Grid 256 WGs x 256 thr:
//     WG 0..63   : R11 recurrence (split-poll 32/wave + LDS pair-exchange
//                  + 1 barrier + in-wave 4x4 transpose), all 1024 steps.
//     WG 64..255 : pregate producers (32 col-blocks x 6 t-slices; 4 waves
//                  = (batch-half, gate-pair), bfrag 2x16/wave).
//
// Fallbacks: R11 chunked two-phase; R4 single kernel.

#define T_STEPS 1024
#define BATCH   32
#define DIN     512
#define H       512
#define NWG     64
#define NPRE    192
#define HC      8
#define XSTRIDE 520        // f16 elems; 1040B row = bank offset 4 -> 2-way max (free)
#define GSTRIDE 34         // padded f32 row stride (R4 fallback only)
#define RECS_PER_PARITY 8192   // 16 kk * 512   (R4 record format)
#define PGRING  128            // pre-gate ring slots (32 MB)

typedef _Float16 half8  __attribute__((ext_vector_type(8)));
typedef _Float16 half4v __attribute__((ext_vector_type(4)));
typedef float    f32x4  __attribute__((ext_vector_type(4)));
typedef unsigned int u32;
typedef unsigned long long u64;
typedef u32 u32x4 __attribute__((ext_vector_type(4)));

#define AT_LD_U64(p)   __hip_atomic_load((const u64*)(p), __ATOMIC_RELAXED, __HIP_MEMORY_SCOPE_AGENT)
#define AT_ST_U64(p,v) __hip_atomic_store((u64*)(p), (v), __ATOMIC_RELAXED, __HIP_MEMORY_SCOPE_AGENT)

__device__ __forceinline__ float sigmoidf_(float x) {
    return 1.0f / (1.0f + __expf(-x));
}
__device__ __forceinline__ float tanhf_(float x) {
    return 1.0f - 2.0f / (1.0f + __expf(2.0f * x));
}
__device__ __forceinline__ float f16lo_(u32 w) {
    return (float)__builtin_bit_cast(_Float16, (unsigned short)(w & 0xffffu));
}
__device__ __forceinline__ float f16hi_(u32 w) {
    return (float)__builtin_bit_cast(_Float16, (unsigned short)(w >> 16));
}

// ======================= fused kernel ===================================
__global__ __launch_bounds__(256, 1) void lstm_fused(
    const float* __restrict__ x,
    const float* __restrict__ init_states,
    const float* __restrict__ Wi, const float* __restrict__ Wf,
    const float* __restrict__ Wc, const float* __restrict__ Wo,
    const float* __restrict__ Ui, const float* __restrict__ Uf,
    const float* __restrict__ Uc, const float* __restrict__ Uo,
    const float* __restrict__ bi, const float* __restrict__ bf,
    const float* __restrict__ bc, const float* __restrict__ bo,
    float* __restrict__ out,
    u64*   __restrict__ pgrec,    // ring: [128][64wg][4wave][64lane][2] u64
    u64*   __restrict__ hrec,     // 2 parities x 8192 records
    int*   __restrict__ progress) // recur WG0 step watermark
{
    __shared__ __align__(16) char smem[2 * BATCH * XSTRIDE * 2];  // 66,560 B

    const int tid  = threadIdx.x;
    const int wg   = blockIdx.x;
    const int lane = tid & 63;
    const int wave = tid >> 6;

    if (wg < NWG) {
        // ================= recur role (R11 protocol + pgrec poll) ========
        u32* share = (u32*)smem;   // [par][mt][kk][lane][4] u32
        auto shp = [&](int par, int mtv, int kk, int ln) -> u32* {
            return &share[(((par * 2 + mtv) * 16 + kk) * 64 + ln) * 4];
        };

        const int mt = wave & 1;
        const int nt = wave >> 1;
        const int n_local = lane & 15;
        const int kq = lane >> 4;
        const int row = mt * 16 + n_local;      // A-frag batch row (poll id)

        const int gi   = n_local >> 2;          // gate of this lane's n-col
        const int cl   = n_local & 3;
        const int ejl  = nt * 4 + cl;           // local h-col 0..7
        const int wcol = wg * HC + ejl;
        const int eb   = mt * 16 + kq * 4 + gi; // post-transpose owned batch
        const int ecol = wcol;

        float c_state = init_states[BATCH * H + eb * H + ecol];
        const int widx = (wg >> 2) * 512 + (ejl >> 1) * 128 + eb * 4 + (wg & 3);

        // publish h0 (epoch 1, parity 0)
        {
            _Float16 h0 = (_Float16)init_states[eb * H + ecol];
            u32 hu  = (u32)__builtin_bit_cast(unsigned short, h0);
            u32 oth = __shfl_down(hu, 1);
            if ((lane & 1) == 0)
                AT_ST_U64(&hrec[widx], ((u64)1u << 32) | (u64)(hu | (oth << 16)));
        }

        // one-time: U B-fragments
        const float* Umat = (gi == 0) ? Ui : (gi == 1) ? Uf : (gi == 2) ? Uc : Uo;
        half8 bfrag[16];
        #pragma unroll
        for (int kk = 0; kk < 16; ++kk) {
            #pragma unroll
            for (int jj = 0; jj < 8; ++jj) {
                int k = kk * 32 + kq * 8 + jj;
                bfrag[kk][jj] = (_Float16)Umat[k * H + wcol];
            }
        }

        // consumer pgrec base (per wave): +lane*2 per lane
        const size_t pgwbase = ((size_t)wg * 4 + wave) * 128;

        const int ridx_base = row * 4 + kq;
        const int kk0 = nt * 8;
        const bool q0 = (lane >> 2) & 1;
        const bool q1 = (lane >> 3) & 1;

        for (int t = 0; t < T_STEPS; ++t) {
            const u64* rb = hrec + (size_t)(t & 1) * RECS_PER_PARITY;
            const u32 target = (u32)(t + 1);
            const int par = t & 1;
            const u64* pb =
                pgrec + (size_t)(t & (PGRING - 1)) * (NWG * 4 * 128) + pgwbase
                      + lane * 2;

            // ---- poll OWN 32 h-records + 2 pg-records (one loop) --------
            u64 rec[32];
            u64 pr0, pr1;
            unsigned spins = 0;
            for (;;) {
                #pragma unroll
                for (int kk2 = 0; kk2 < 8; ++kk2) {
                    #pragma unroll
                    for (int s = 0; s < 4; ++s)
                        rec[kk2 * 4 + s] =
                            AT_LD_U64(&rb[(kk0 + kk2) * 512 + s * 128 + ridx_base]);
                }
                pr0 = AT_LD_U64(pb);
                pr1 = AT_LD_U64(pb + 1);
                int ok = ((u32)(pr0 >> 32) == target)
                       & ((u32)(pr1 >> 32) == target);
                #pragma unroll
                for (int i = 0; i < 32; ++i)
                    ok &= ((u32)(rec[i] >> 32) == target);
                if (__all(ok)) break;
                if (++spins > 2000000u) break;   // safety valve
            }

            // unpack pre-gate (x@W + b) from the 2 records
            f32x4 pg;
            pg[0] = f16lo_((u32)pr0);  pg[1] = f16hi_((u32)pr0);
            pg[2] = f16lo_((u32)pr1);  pg[3] = f16hi_((u32)pr1);

            // ---- publish own payloads to LDS (parity bank) --------------
            #pragma unroll
            for (int kk2 = 0; kk2 < 8; ++kk2) {
                u32x4 v = { (u32)rec[kk2 * 4 + 0], (u32)rec[kk2 * 4 + 1],
                            (u32)rec[kk2 * 4 + 2], (u32)rec[kk2 * 4 + 3] };
                *(u32x4*)shp(par, mt, kk0 + kk2, lane) = v;
            }

            __syncthreads();   // the ONLY barrier per step

            // ---- read all 16 kk A-frag payloads from LDS ----------------
            u32x4 au[16];
            #pragma unroll
            for (int kk = 0; kk < 16; ++kk)
                au[kk] = *(const u32x4*)shp(par, mt, kk, lane);

            // ---- h-half matmul; acc starts at pre-gate ------------------
            f32x4 acc  = pg;
            f32x4 acc2 = {0.f, 0.f, 0.f, 0.f};
            #pragma unroll
            for (int kk = 0; kk < 16; kk += 2) {
                union { u32x4 v; half8 h; } a0, a1;
                a0.v = au[kk];
                a1.v = au[kk + 1];
                acc  = __builtin_amdgcn_mfma_f32_16x16x32_f16(a0.h, bfrag[kk],     acc,  0, 0, 0);
                acc2 = __builtin_amdgcn_mfma_f32_16x16x32_f16(a1.h, bfrag[kk + 1], acc2, 0, 0, 0);
            }
            float a0v = acc[0] + acc2[0];
            float a1v = acc[1] + acc2[1];
            float a2v = acc[2] + acc2[2];
            float a3v = acc[3] + acc2[3];

            // ---- in-wave 4x4 transpose (gate axis <-> r axis) -----------
            float t0_ = __shfl_xor(a1v, 4);
            float t1_ = __shfl_xor(a0v, 4);
            float t2_ = __shfl_xor(a3v, 4);
            float t3_ = __shfl_xor(a2v, 4);
            float b0 = q0 ? t0_ : a0v;
            float b1 = q0 ? a1v : t1_;
            float b2 = q0 ? t2_ : a2v;
            float b3 = q0 ? a3v : t3_;
            float u0 = __shfl_xor(b2, 8);
            float u1 = __shfl_xor(b3, 8);
            float u2 = __shfl_xor(b0, 8);
            float u3 = __shfl_xor(b1, 8);
            float pi  = q1 ? u0 : b0;
            float pf  = q1 ? u1 : b1;
            float pgg = q1 ? b2 : u2;
            float po  = q1 ? b3 : u3;

            // ---- gates + state update + immediate publish ---------------
            float ig = sigmoidf_(pi);
            float fg = sigmoidf_(pf);
            float gg = tanhf_(pgg);
            float og = sigmoidf_(po);
            c_state  = fg * c_state + ig * gg;
            float h_val = og * tanhf_(c_state);

            if (t + 1 < T_STEPS) {
                _Float16 hh = (_Float16)h_val;
                u32 hu  = (u32)__builtin_bit_cast(unsigned short, hh);
                u32 oth = __shfl_down(hu, 1);
                if ((lane & 1) == 0) {
                    AT_ST_U64(&hrec[(size_t)((t + 1) & 1) * RECS_PER_PARITY + widx],
                              ((u64)(u32)(t + 2) << 32) | (u64)(hu | (oth << 16)));
                }
            }

            // off-critical-path tail
            out[((size_t)eb * T_STEPS + t) * H + ecol] = h_val;
            if (wg == 0 && tid == 0)
                __hip_atomic_store(progress, t, __ATOMIC_RELAXED,
                                   __HIP_MEMORY_SCOPE_AGENT);
        }
    } else {
        // ================= pregate role =================================
        _Float16* xbuf = (_Float16*)smem;   // [2][BATCH][XSTRIDE]

        const int g2  = wg - NWG;           // 0..191
        const int cb  = g2 & 31;            // h-cols [cb*16, cb*16+16)
        const int tsl = g2 >> 5;            // t-slice 0..5: t = tsl + 6k
        const int mt  = wave & 1;           // batch half
        const int gp  = wave >> 1;          // gate pair: gates {2gp, 2gp+1}
        const int n_local = lane & 15;
        const int kq  = lane >> 4;
        const int row = mt * 16 + n_local;
        const int hcol = cb * 16 + n_local;

        const float* W0  = (gp == 0) ? Wi : Wc;   // gate 2gp
        const float* W1  = (gp == 0) ? Wf : Wo;   // gate 2gp+1
        const float* b0p = (gp == 0) ? bi : bc;
        const float* b1p = (gp == 0) ? bf : bo;
        const float bv0 = b0p[hcol];
        const float bv1 = b1p[hcol];

        half8 bw0[16], bw1[16];             // 128 VGPRs
        #pragma unroll
        for (int kk = 0; kk < 16; ++kk) {
            #pragma unroll
            for (int jj = 0; jj < 8; ++jj) {
                int k = kk * 32 + kq * 8 + jj;
                bw0[kk][jj] = (_Float16)W0[k * H + hcol];
                bw1[kk][jj] = (_Float16)W1[k * H + hcol];
            }
        }

        // consumer-layout address pieces (records land where recur reads)
        const int wgc   = hcol >> 3;            // consumer WG
        const int ejl   = hcol & 7;
        const int wavec = ((ejl >> 2) << 1) + mt;
        const int cl    = ejl & 3;
        const size_t cwbase = ((size_t)wgc * 4 + wavec) * 128;
        const int l0 = (kq * 16 + (gp * 2) * 4 + cl) * 2;      // gate 2gp
        const int l1 = (kq * 16 + (gp * 2 + 1) * 4 + cl) * 2;  // gate 2gp+1

        auto pack2 = [&](float a, float b, u32 ep) -> u64 {
            u32 lo = (u32)__builtin_bit_cast(unsigned short, (_Float16)a)
                   | ((u32)__builtin_bit_cast(unsigned short, (_Float16)b) << 16);
            return ((u64)ep << 32) | (u64)lo;
        };

        // x staging (f32 -> f16), 256-thread version (R4)
        auto stage = [&](int t, int buf) {
            const int sb = tid >> 3;
            const int so = (tid & 7) * 4;
            const float* xr = x + ((size_t)sb * T_STEPS + t) * DIN;
            _Float16* xb = &xbuf[buf * (BATCH * XSTRIDE)];
            #pragma unroll
            for (int q = 0; q < 16; ++q) {
                int colq = so + q * 32;
                float4 v = *(const float4*)(xr + colq);
                half4v hv = { (_Float16)v.x, (_Float16)v.y,
                              (_Float16)v.z, (_Float16)v.w };
                *(half4v*)&xb[sb * XSTRIDE + colq] = hv;
            }
        };

        stage(tsl, 0);
        stage(tsl + 6, 1);
        __syncthreads();

        for (int k = 0, t = tsl; t < T_STEPS; ++k, t += 6) {
            // ring throttle: slot t&127 last held epoch t-127, consumed by
            // consumers at step t-128; slowest consumer >= progress-1, so
            // require t <= progress + 120 (margin 7).  Poison clamps to 0.
            if (t > PGRING - 8) {
                unsigned sp = 0;
                for (;;) {
                    int p = __hip_atomic_load(progress, __ATOMIC_RELAXED,
                                              __HIP_MEMORY_SCOPE_AGENT);
                    if (p < 0 || p >= T_STEPS) p = 0;
                    if (t <= p + (PGRING - 8)) break;
                    if (++sp > 4000000u) break;   // safety valve
                    __builtin_amdgcn_s_sleep(8);
                }
            }

            const _Float16* xr2 =
                &xbuf[(k & 1) * (BATCH * XSTRIDE) + row * XSTRIDE + kq * 8];
            f32x4 a0 = {0.f,0.f,0.f,0.f}, a1 = {0.f,0.f,0.f,0.f};
            f32x4 a2 = {0.f,0.f,0.f,0.f}, a3 = {0.f,0.f,0.f,0.f};
            #pragma unroll
            for (int kk = 0; kk < 16; kk += 2) {
                half8 v0 = *(const half8*)(xr2 + kk * 32);
                half8 v1 = *(const half8*)(xr2 + (kk + 1) * 32);
                a0 = __builtin_amdgcn_mfma_f32_16x16x32_f16(v0, bw0[kk],     a0, 0, 0, 0);
                a1 = __builtin_amdgcn_mfma_f32_16x16x32_f16(v0, bw1[kk],     a1, 0, 0, 0);
                a2 = __builtin_amdgcn_mfma_f32_16x16x32_f16(v1, bw0[kk + 1], a2, 0, 0, 0);
                a3 = __builtin_amdgcn_mfma_f32_16x16x32_f16(v1, bw1[kk + 1], a3, 0, 0, 0);
            }
            float wA0 = a0[0] + a2[0] + bv0, wA1 = a0[1] + a2[1] + bv0;
            float wA2 = a0[2] + a2[2] + bv0, wA3 = a0[3] + a2[3] + bv0;
            float wB0 = a1[0] + a3[0] + bv1, wB1 = a1[1] + a3[1] + bv1;
            float wB2 = a1[2] + a3[2] + bv1, wB3 = a1[3] + a3[3] + bv1;

            // self-validating record stores (relaxed agent; no ordering
            // needed — each 8B record is individually valid)
            const u32 ep = (u32)(t + 1);
            u64* sb = pgrec + (size_t)(t & (PGRING - 1)) * (NWG * 4 * 128)
                            + cwbase;
            AT_ST_U64(&sb[l0],     pack2(wA0, wA1, ep));
            AT_ST_U64(&sb[l0 + 1], pack2(wA2, wA3, ep));
            AT_ST_U64(&sb[l1],     pack2(wB0, wB1, ep));
            AT_ST_U64(&sb[l1 + 1], pack2(wB2, wB3, ep));

            __syncthreads();   // xbuf double-buffer hazard (not ordering)
            if (t + 12 < T_STEPS) stage(t + 12, k & 1);
        }
    }
}

// ======================= chunked fallback (R11) =========================
__global__ __launch_bounds__(512, 1) void lstm_pregate(
    const float* __restrict__ x,
    const float* __restrict__ Wi, const float* __restrict__ Wf,
    const float* __restrict__ Wc, const float* __restrict__ Wo,
    const float* __restrict__ bi, const float* __restrict__ bf,
    const float* __restrict__ bc, const float* __restrict__ bo,
    float* __restrict__ preg, int t0, int tc)
{
    __shared__ _Float16 xbuf[2 * BATCH * XSTRIDE];

    const int tid  = threadIdx.x;
    const int wg   = blockIdx.x;
    const int cb   = wg & 31;
    const int tq   = wg >> 5;
    const int tcq  = tc >> 3;
    const int tb   = t0 + tq * tcq;
    const int lane = tid & 63;
    const int wave = tid >> 6;
    const int mt   = wave & 1;
    const int gsel = wave >> 1;        // 8 waves REQUIRED
    const int n_local = lane & 15;
    const int kq   = lane >> 4;
    const int row  = mt * 16 + n_local;
    const int hcol = cb * 16 + n_local;

    const float* Wmat = (gsel == 0) ? Wi : (gsel == 1) ? Wf : (gsel == 2) ? Wc : Wo;
    const float* bvec = (gsel == 0) ? bi : (gsel == 1) ? bf : (gsel == 2) ? bc : bo;
    const float bv = bvec[hcol];

    half8 bfrag[16];
    #pragma unroll
    for (int kk = 0; kk < 16; ++kk) {
        #pragma unroll
        for (int jj = 0; jj < 8; ++jj) {
            int k = kk * 32 + kq * 8 + jj;
            bfrag[kk][jj] = (_Float16)Wmat[k * H + hcol];
        }
    }

    auto stage = [&](int t, int buf) {
        const int sb = tid >> 4;
        const int so = (tid & 15) * 4;
        const float* xr = x + ((size_t)sb * T_STEPS + t) * DIN;
        _Float16* xb = &xbuf[buf * (BATCH * XSTRIDE)];
        #pragma unroll
        for (int q = 0; q < 8; ++q) {
            int colq = so + q * 64;
            float4 v = *(const float4*)(xr + colq);
            half4v hv = { (_Float16)v.x, (_Float16)v.y,
                          (_Float16)v.z, (_Float16)v.w };
            *(half4v*)&xb[sb * XSTRIDE + colq] = hv;
        }
    };

    stage(tb, 0);
    stage(tb + 1, 1);
    __syncthreads();

    for (int lt = 0; lt < tcq; ++lt) {
        f32x4 a0 = {0.f,0.f,0.f,0.f};
        f32x4 a1 = {0.f,0.f,0.f,0.f};
        const _Float16* xr2 =
            &xbuf[(lt & 1) * (BATCH * XSTRIDE) + row * XSTRIDE + kq * 8];
        #pragma unroll
        for (int kk = 0; kk < 16; kk += 2) {
            half8 v0 = *(const half8*)(xr2 + kk * 32);
            half8 v1 = *(const half8*)(xr2 + (kk + 1) * 32);
            a0 = __builtin_amdgcn_mfma_f32_16x16x32_f16(v0, bfrag[kk],     a0, 0, 0, 0);
            a1 = __builtin_amdgcn_mfma_f32_16x16x32_f16(v1, bfrag[kk + 1], a1, 0, 0, 0);
        }
        f32x4 aw;
        #pragma unroll
        for (int r = 0; r < 4; ++r) aw[r] = a0[r] + a1[r] + bv;

        const size_t base =
            (((size_t)(tb - t0 + lt) * 4 + gsel) * 512 + hcol) * 32
            + mt * 16 + kq * 4;
        *(f32x4*)&preg[base] = aw;

        __syncthreads();
        if (lt + 2 < tcq) stage(tb + lt + 2, lt & 1);
    }
}

__global__ __launch_bounds__(256, 1) void lstm_recur(
    const float* __restrict__ init_states,
    const float* __restrict__ Ui, const float* __restrict__ Uf,
    const float* __restrict__ Uc, const float* __restrict__ Uo,
    const float* __restrict__ preg,
    float* __restrict__ out,
    u64* __restrict__ hrec,
    float* __restrict__ cst,
    int t0, int tc)
{
    __shared__ u32 share[2][2][16][64][4];

    const int tid  = threadIdx.x;
    const int wg   = blockIdx.x;
    const int lane = tid & 63;
    const int wave = tid >> 6;
    const int mt   = wave & 1;
    const int nt   = wave >> 1;
    const int n_local = lane & 15;
    const int kq   = lane >> 4;
    const int row  = mt * 16 + n_local;

    const int gi   = n_local >> 2;
    const int cl   = n_local & 3;
    const int ejl  = nt * 4 + cl;
    const int wcol = wg * HC + ejl;
    const int eb   = mt * 16 + kq * 4 + gi;
    const int ecol = wcol;

    float c_state = (t0 == 0) ? init_states[BATCH * H + eb * H + ecol]
                              : cst[eb * H + ecol];

    const int widx = (wg >> 2) * 512 + (ejl >> 1) * 128 + eb * 4 + (wg & 3);

    if (t0 == 0) {
        _Float16 h0 = (_Float16)init_states[eb * H + ecol];
        u32 hu  = (u32)__builtin_bit_cast(unsigned short, h0);
        u32 oth = __shfl_down(hu, 1);
        if ((lane & 1) == 0)
            AT_ST_U64(&hrec[widx], ((u64)1u << 32) | (u64)(hu | (oth << 16)));
    }

    const float* Umat = (gi == 0) ? Ui : (gi == 1) ? Uf : (gi == 2) ? Uc : Uo;
    half8 bfrag[16];
    #pragma unroll
    for (int kk = 0; kk < 16; ++kk) {
        #pragma unroll
        for (int jj = 0; jj < 8; ++jj) {
            int k = kk * 32 + kq * 8 + jj;
            bfrag[kk][jj] = (_Float16)Umat[k * H + wcol];
        }
    }

    const size_t pgbase =
        ((size_t)gi * 512 + wcol) * 32 + mt * 16 + kq * 4;
    f32x4 pg = *(const f32x4*)&preg[pgbase];

    const int ridx_base = row * 4 + kq;
    const int kk0 = nt * 8;
    const bool q0 = (lane >> 2) & 1;
    const bool q1 = (lane >> 3) & 1;

    for (int lt = 0; lt < tc; ++lt) {
        const int gt = t0 + lt;
        const u64* rb = hrec + (size_t)(gt & 1) * RECS_PER_PARITY;
        const u32 target = (u32)(gt + 1);
        const int par = gt & 1;

        u64 rec[32];
        unsigned spins = 0;
        for (;;) {
            #pragma unroll
            for (int kk2 = 0; kk2 < 8; ++kk2) {
                #pragma unroll
                for (int s = 0; s < 4; ++s)
                    rec[kk2 * 4 + s] =
                        AT_LD_U64(&rb[(kk0 + kk2) * 512 + s * 128 + ridx_base]);
            }
            int ok = 1;
            #pragma unroll
            for (int i = 0; i < 32; ++i)
                ok &= ((u32)(rec[i] >> 32) == target);
            if (__all(ok)) break;
            if (++spins > 300000u) break;
        }

        #pragma unroll
        for (int kk2 = 0; kk2 < 8; ++kk2) {
            u32x4 v = { (u32)rec[kk2 * 4 + 0], (u32)rec[kk2 * 4 + 1],
                        (u32)rec[kk2 * 4 + 2], (u32)rec[kk2 * 4 + 3] };
            *(u32x4*)&share[par][mt][kk0 + kk2][lane][0] = v;
        }

        f32x4 pgn = pg;
        if (lt + 1 < tc)
            pgn = *(const f32x4*)&preg[(size_t)(lt + 1) * 65536 + pgbase];

        __syncthreads();

        u32x4 au[16];
        #pragma unroll
        for (int kk = 0; kk < 16; ++kk)
            au[kk] = *(const u32x4*)&share[par][mt][kk][lane][0];

        f32x4 acc  = pg;
        f32x4 acc2 = {0.f, 0.f, 0.f, 0.f};
        #pragma unroll
        for (int kk = 0; kk < 16; kk += 2) {
            union { u32x4 v; half8 h; } a0, a1;
            a0.v = au[kk];
            a1.v = au[kk + 1];
            acc  = __builtin_amdgcn_mfma_f32_16x16x32_f16(a0.h, bfrag[kk],     acc,  0, 0, 0);
            acc2 = __builtin_amdgcn_mfma_f32_16x16x32_f16(a1.h, bfrag[kk + 1], acc2, 0, 0, 0);
        }
        float a0v = acc[0] + acc2[0];
        float a1v = acc[1] + acc2[1];
        float a2v = acc[2] + acc2[2];
        float a3v = acc[3] + acc2[3];

        float t0_ = __shfl_xor(a1v, 4);
        float t1_ = __shfl_xor(a0v, 4);
        float t2_ = __shfl_xor(a3v, 4);
        float t3_ = __shfl_xor(a2v, 4);
        float b0 = q0 ? t0_ : a0v;
        float b1 = q0 ? a1v : t1_;
        float b2 = q0 ? t2_ : a2v;
        float b3 = q0 ? a3v : t3_;
        float u0 = __shfl_xor(b2, 8);
        float u1 = __shfl_xor(b3, 8);
        float u2 = __shfl_xor(b0, 8);
        float u3 = __shfl_xor(b1, 8);
        float pi  = q1 ? u0 : b0;
        float pf  = q1 ? u1 : b1;
        float pgg = q1 ? b2 : u2;
        float po  = q1 ? b3 : u3;

        float ig = sigmoidf_(pi);
        float fg = sigmoidf_(pf);
        float gg = tanhf_(pgg);
        float og = sigmoidf_(po);
        c_state  = fg * c_state + ig * gg;
        float h_val = og * tanhf_(c_state);

        if (gt + 1 < T_STEPS) {
            _Float16 hh = (_Float16)h_val;
            u32 hu  = (u32)__builtin_bit_cast(unsigned short, hh);
            u32 oth = __shfl_down(hu, 1);
            if ((lane & 1) == 0) {
                AT_ST_U64(&hrec[(size_t)((gt + 1) & 1) * RECS_PER_PARITY + widx],
                          ((u64)(u32)(gt + 2) << 32) | (u64)(hu | (oth << 16)));
            }
        }

        out[((size_t)eb * T_STEPS + gt) * H + ecol] = h_val;
        pg = pgn;
    }

    cst[eb * H + ecol] = c_state;
}

// ======================= fallback: R4 single kernel =====================
__global__ __launch_bounds__(256, 1) void lstm_persistent_fb(
    const float* __restrict__ x,
    const float* __restrict__ init_states,
    const float* __restrict__ Wi, const float* __restrict__ Ui, const float* __restrict__ bi,
    const float* __restrict__ Wf, const float* __restrict__ Uf, const float* __restrict__ bf,
    const float* __restrict__ Wc, const float* __restrict__ Uc, const float* __restrict__ bc,
    const float* __restrict__ Wo, const float* __restrict__ Uo, const float* __restrict__ bo,
    float* __restrict__ out,
    u64* __restrict__ hrec)
{
    __shared__ _Float16 xbuf[2 * BATCH * XSTRIDE];
    __shared__ float    gbuf[2 * BATCH * GSTRIDE];

    const int tid  = threadIdx.x;
    const int wg   = blockIdx.x;
    const int lane = tid & 63;
    const int wave = tid >> 6;
    const int mt   = wave & 1;
    const int nt   = wave >> 1;
    const int row  = mt * 16 + (lane & 15);
    const int kq   = lane >> 4;

    const int eb   = tid >> 3;
    const int ej   = tid & 7;
    const int ecol = wg * HC + ej;

    float c_state = init_states[BATCH * H + eb * H + ecol];
    {
        _Float16 h0 = (_Float16)init_states[eb * H + ecol];
        u32 hu  = (u32)__builtin_bit_cast(unsigned short, h0);
        u32 oth = __shfl_down(hu, 1);
        if ((tid & 1) == 0) {
            const int ridx = (wg >> 2) * 512 + (ej >> 1) * 128 + eb * 4 + (wg & 3);
            AT_ST_U64(&hrec[ridx], ((u64)1u << 32) | (u64)(hu | (oth << 16)));
        }
    }

    const int n_local = lane & 15;
    const int gi   = nt * 2 + (n_local >> 3);
    const int wcol = wg * HC + (n_local & 7);
    const float* Wmat = (gi == 0) ? Wi : (gi == 1) ? Wf : (gi == 2) ? Wc : Wo;
    const float* Umat = (gi == 0) ? Ui : (gi == 1) ? Uf : (gi == 2) ? Uc : Uo;

    half8 bfrag[32];
    #pragma unroll
    for (int kk = 0; kk < 16; ++kk) {
        #pragma unroll
        for (int jj = 0; jj < 8; ++jj) {
            int k = kk * 32 + kq * 8 + jj;
            bfrag[kk][jj]      = (_Float16)Wmat[k * H + wcol];
            bfrag[16 + kk][jj] = (_Float16)Umat[k * H + wcol];
        }
    }

    const float bi_v = bi[ecol], bf_v = bf[ecol], bc_v = bc[ecol], bo_v = bo[ecol];

    auto stage = [&](int t, int buf) {
        const int sb = tid >> 3;
        const int so = (tid & 7) * 4;
        const float* xr = x + ((size_t)sb * T_STEPS + t) * DIN;
        _Float16* xb = &xbuf[buf * (BATCH * XSTRIDE)];
        #pragma unroll
        for (int q = 0; q < 16; ++q) {
            int colq = so + q * 32;
            float4 v = *(const float4*)(xr + colq);
            half4v hv = { (_Float16)v.x, (_Float16)v.y,
                          (_Float16)v.z, (_Float16)v.w };
            *(half4v*)&xb[sb * XSTRIDE + colq] = hv;
        }
    };
    auto xmm = [&](int buf) -> f32x4 {
        f32x4 ax  = {0.f, 0.f, 0.f, 0.f};
        f32x4 ax2 = {0.f, 0.f, 0.f, 0.f};
        const _Float16* xr2 = &xbuf[buf * (BATCH * XSTRIDE) + row * XSTRIDE + kq * 8];
        #pragma unroll
        for (int kk = 0; kk < 16; kk += 2) {
            half8 a0 = *(const half8*)(xr2 + kk * 32);
            half8 a1 = *(const half8*)(xr2 + (kk + 1) * 32);
            ax  = __builtin_amdgcn_mfma_f32_16x16x32_f16(a0, bfrag[kk],     ax,  0, 0, 0);
            ax2 = __builtin_amdgcn_mfma_f32_16x16x32_f16(a1, bfrag[kk + 1], ax2, 0, 0, 0);
        }
        #pragma unroll
        for (int r = 0; r < 4; ++r) ax[r] += ax2[r];
        return ax;
    };

    stage(0, 0);
    stage(1, 1);
    __syncthreads();
    f32x4 acc_x = xmm(0);

    const int ridx_base = row * 4 + kq;
    const int widx = (wg >> 2) * 512 + (ej >> 1) * 128 + eb * 4 + (wg & 3);

    for (int t = 0; t < T_STEPS; ++t) {
        const u64* rb = hrec + (size_t)(t & 1) * RECS_PER_PARITY;
        const u32 target = (u32)(t + 1);

        u64 rec[64];
        unsigned spins = 0;
        for (;;) {
            #pragma unroll
            for (int kk = 0; kk < 16; ++kk) {
                #pragma unroll
                for (int s = 0; s < 4; ++s)
                    rec[kk * 4 + s] = AT_LD_U64(&rb[kk * 512 + s * 128 + ridx_base]);
            }
            int ok = 1;
            #pragma unroll
            for (int i = 0; i < 64; ++i)
                ok &= ((u32)(rec[i] >> 32) == target);
            if (__all(ok)) break;
            if (++spins > 300000u) break;
        }

        float* gb = &gbuf[(t & 1) * (BATCH * GSTRIDE)];
        {
            f32x4 acc  = acc_x;
            f32x4 acc2 = {0.f, 0.f, 0.f, 0.f};
            #pragma unroll
            for (int kk = 0; kk < 16; kk += 2) {
                union { u32 d[4]; half8 h; } a0, a1;
                #pragma unroll
                for (int s = 0; s < 4; ++s) {
                    a0.d[s] = (u32)rec[kk * 4 + s];
                    a1.d[s] = (u32)rec[(kk + 1) * 4 + s];
                }
                acc  = __builtin_amdgcn_mfma_f32_16x16x32_f16(a0.h, bfrag[16 + kk],     acc,  0, 0, 0);
                acc2 = __builtin_amdgcn_mfma_f32_16x16x32_f16(a1.h, bfrag[16 + kk + 1], acc2, 0, 0, 0);
            }
            #pragma unroll
            for (int r = 0; r < 4; ++r) {
                gb[(mt * 16 + kq * 4 + r) * GSTRIDE + nt * 16 + n_local] =
                    acc[r] + acc2[r];
            }
        }
        __syncthreads();

        float h_val;
        {
            float pi = gb[eb * GSTRIDE + ej]      + bi_v;
            float pf = gb[eb * GSTRIDE + 8 + ej]  + bf_v;
            float pg = gb[eb * GSTRIDE + 16 + ej] + bc_v;
            float po = gb[eb * GSTRIDE + 24 + ej] + bo_v;
            float ig = sigmoidf_(pi);
            float fg = sigmoidf_(pf);
            float gg = tanhf_(pg);
            float og = sigmoidf_(po);
            c_state  = fg * c_state + ig * gg;
            h_val    = og * tanhf_(c_state);

            if (t + 1 < T_STEPS) {
                _Float16 hh = (_Float16)h_val;
                u32 hu  = (u32)__builtin_bit_cast(unsigned short, hh);
                u32 oth = __shfl_down(hu, 1);
                if ((tid & 1) == 0) {
                    AT_ST_U64(&hrec[(size_t)((t + 1) & 1) * RECS_PER_PARITY + widx],
                              ((u64)(u32)(t + 2) << 32) | (u64)(hu | (oth << 16)));
                }
            }
        }

        out[((size_t)eb * T_STEPS + t) * H + ecol] = h_val;
        if (t + 1 < T_STEPS) {
            acc_x = xmm((t + 1) & 1);
            if (t + 2 < T_STEPS) stage(t + 2, t & 1);
        }
    }
}

// ======================= launcher ======================================
extern "C" void kernel_launch(void* const* d_in, const int* in_sizes, int n_in,
                              void* d_out, int out_size, void* d_ws, size_t ws_size,
                              hipStream_t stream) {
    const float* x           = (const float*)d_in[0];
    const float* init_states = (const float*)d_in[1];
    const float* Wi = (const float*)d_in[2];
    const float* Ui = (const float*)d_in[3];
    const float* bi = (const float*)d_in[4];
    const float* Wf = (const float*)d_in[5];
    const float* Uf = (const float*)d_in[6];
    const float* bf = (const float*)d_in[7];
    const float* Wc = (const float*)d_in[8];
    const float* Uc = (const float*)d_in[9];
    const float* bc = (const float*)d_in[10];
    const float* Wo = (const float*)d_in[11];
    const float* Uo = (const float*)d_in[12];
    const float* bo = (const float*)d_in[13];
    float* out = (float*)d_out;

    const size_t PGREC_BYTES = (size_t)PGRING * NWG * 4 * 128 * 8; // 33,554,432
    const size_t HREC_BYTES  = (size_t)2 * RECS_PER_PARITY * 8;    // 128 KB
    const size_t PROG_BYTES  = 64;
    const size_t CST_BYTES   = (size_t)BATCH * H * 4;              //  64 KB

    if (ws_size >= PGREC_BYTES + HREC_BYTES + PROG_BYTES) {
        // -------- fused single-launch path --------
        u64* pgrec = (u64*)d_ws;
        u64* hrec  = (u64*)((char*)d_ws + PGREC_BYTES);
        int* progress = (int*)((char*)d_ws + PGREC_BYTES + HREC_BYTES);

        lstm_fused<<<dim3(NWG + NPRE), dim3(256), 0, stream>>>(
            x, init_states, Wi, Wf, Wc, Wo, Ui, Uf, Uc, Uo,
            bi, bf, bc, bo, out, pgrec, hrec, progress);
        return;
    }

    // -------- chunked two-phase fallback (R11) --------
    static const int cands[] = {512, 256, 128, 64, 32, 16};
    int tc = 0;
    size_t preg_bytes = 0;
    for (int i = 0; i < 6; ++i) {
        size_t pb = (size_t)cands[i] * 2048 * 32 * 4;
        if (ws_size >= pb + HREC_BYTES + CST_BYTES) { tc = cands[i]; preg_bytes = pb; break; }
    }

    if (tc > 0) {
        float* preg = (float*)d_ws;
        u64*   hrec = (u64*)((char*)d_ws + preg_bytes);
        float* cst  = (float*)((char*)d_ws + preg_bytes + HREC_BYTES);

        const int nchunks = T_STEPS / tc;
        for (int c = 0; c < nchunks; ++c) {
            lstm_pregate<<<dim3(256), dim3(512), 0, stream>>>(
                x, Wi, Wf, Wc, Wo, bi, bf, bc, bo, preg, c * tc, tc);
            lstm_recur<<<dim3(NWG), dim3(256), 0, stream>>>(
                init_states, Ui, Uf, Uc, Uo, preg, out, hrec, cst, c * tc, tc);
        }
    } else {
        u64* hrec = (u64*)d_ws;
        lstm_persistent_fb<<<dim3(NWG), dim3(256), 0, stream>>>(
            x, init_states, Wi, Ui, bi, Wf, Uf, bf, Wc, Uc, bc, Wo, Uo, bo,
            out, hrec);
    }
}